// Round 16
// baseline (85.319 us; speedup 1.0000x reference)
//
#include <hip/hip_runtime.h>
#include <stdint.h>

#define BB 32
#define NN 8000
#define MM 256
#define LL (NN + MM)        // 8256
#define NSAMP 512
#define MAXPOS 128
#define T2 1024
#define CH ((LL + T2 - 1) / T2)   // 9
#define SPLIT 4
#define MSUB (MM / SPLIT)   // 64

// forbid fp-contract across this value (exact-path: match numpy rounding)
__device__ __forceinline__ void opaquef(float& x) { asm("" : "+v"(x)); }

__device__ __forceinline__ float rlane(float v, int m)
{
    return __uint_as_float(
        (uint32_t)__builtin_amdgcn_readlane((int)__float_as_uint(v), m));
}

// ---------------- kernel 1: per-(b, box-pair, split) argmax over 64 gts ----
// ZERO-LDS inner loop: each lane holds gt[sp*64+lane] (4 coords + exact a2)
// in VGPRs; iteration m broadcasts lane m via v_readlane into SGPRs (no LDS
// pipe -- the 4-SIMDs-share-one-LDS-pipe contention was the measured floor).
// Rank by u = inter/(a1+a2) (monotone in IoU). key = (u_bits & ~63)|(63-m):
// argmax is ONE v_max_u32; truncated-u ties pick smaller m. Winner provably
// the reference's rounded-quotient argmax when the truncated gap to the
// runner-up > 64 ulp (2^-19 rel >> 2^-22 fast-path + 2^-23 reference
// rounding); else exact serial redo (readlane too). Invalid gts (-1 coords)
// give inter == 0 for every box -> never win, never redo; s clamped so
// 0-area cases give u = 0, never NaN. Zero-q rows classify background
// downstream -> midx output-invisible.
__global__ __launch_bounds__(256) void match_split_kernel(
    const float* __restrict__ boxes, const float* __restrict__ gt,
    uint32_t* __restrict__ keys)
{
    const int b = blockIdx.y, sp = blockIdx.z, tid = threadIdx.x;
    const int lane = tid & 63;

    // gt tile in registers: lane k holds gt[sp*64+k] (loaded before any exit)
    float4 vg = ((const float4*)(gt + ((size_t)b * MM + sp * MSUB) * 4))[lane];
    float va2 = (vg.z - vg.x) * (vg.w - vg.y); opaquef(va2);   // exact fl

    const int l0 = blockIdx.x * 512 + tid * 2;
    if (l0 >= LL) return;
    const int l1 = l0 + 1;
    const bool v1 = (l1 < LL);
    const int l1c = v1 ? l1 : l0;

    const float4* bb4 = (const float4*)(boxes + (size_t)b * NN * 4);
    const float4* gb4 = (const float4*)(gt + (size_t)b * MM * 4);
    float4 bx0 = (l0 < NN) ? bb4[l0] : gb4[l0 - NN];
    float4 bx1 = (l1c < NN) ? bb4[l1c] : gb4[l1c - NN];
    float a10 = (bx0.z - bx0.x) * (bx0.w - bx0.y); opaquef(a10);
    float a11 = (bx1.z - bx1.x) * (bx1.w - bx1.y); opaquef(a11);

    uint32_t best0 = 0, sec0 = 0, best1 = 0, sec1 = 0;
    #pragma unroll 16
    for (int m = 0; m < MSUB; ++m) {
        const float gy0 = rlane(vg.x, m), gx0 = rlane(vg.y, m);
        const float gy1 = rlane(vg.z, m), gx1 = rlane(vg.w, m);
        const float a2  = rlane(va2,  m);
        {
            float ih = fmaxf(fminf(bx0.z, gy1) - fmaxf(bx0.x, gy0), 0.0f);
            float iw = fmaxf(fminf(bx0.w, gx1) - fmaxf(bx0.y, gx0), 0.0f);
            float inter = ih * iw;
            float s = fmaxf(a10 + a2, 1e-30f);
            float u = inter * __builtin_amdgcn_rcpf(s);
            uint32_t key = (__float_as_uint(u) & 0xFFFFFFC0u)
                         | (uint32_t)(63 - m);
            sec0  = max(sec0, min(best0, key));
            best0 = max(best0, key);
        }
        {
            float ih = fmaxf(fminf(bx1.z, gy1) - fmaxf(bx1.x, gy0), 0.0f);
            float iw = fmaxf(fminf(bx1.w, gx1) - fmaxf(bx1.y, gx0), 0.0f);
            float inter = ih * iw;
            float s = fmaxf(a11 + a2, 1e-30f);
            float u = inter * __builtin_amdgcn_rcpf(s);
            uint32_t key = (__float_as_uint(u) & 0xFFFFFFC0u)
                         | (uint32_t)(63 - m);
            sec1  = max(sec1, min(best1, key));
            best1 = max(best1, key);
        }
    }

    bool redo0 = ((best0 & ~63u) != 0u) &&
                 (((best0 & ~63u) - (sec0 & ~63u)) <= 64u);
    bool redo1 = v1 && ((best1 & ~63u) != 0u) &&
                 (((best1 & ~63u) - (sec1 & ~63u)) <= 64u);
    if (__any(redo0 || redo1)) {
        // exact reference semantics, serial, via readlane (rare)
        #define SERIAL(BX, A1, BEST, RD)                                     \
        if (RD) {                                                            \
            float qb = -1.0f; int bi = 0;                                    \
            for (int m = 0; m < MSUB; ++m) {                                 \
                float gy0 = rlane(vg.x, m), gx0 = rlane(vg.y, m);            \
                float gy1 = rlane(vg.z, m), gx1 = rlane(vg.w, m);            \
                float a2  = rlane(va2,  m);                                  \
                float ih = fmaxf(fminf(BX.z, gy1) - fmaxf(BX.x, gy0), 0.0f); \
                float iw = fmaxf(fminf(BX.w, gx1) - fmaxf(BX.y, gx0), 0.0f); \
                float inter = ih * iw; opaquef(inter);                       \
                float uni = (A1 + a2) - inter;   /* numpy order/rounding */  \
                float q = (uni > 0.0f) ? (inter / uni) : 0.0f;               \
                if (q > qb) { qb = q; bi = m; }                              \
            }                                                                \
            float gy0 = rlane(vg.x, bi), gx0 = rlane(vg.y, bi);              \
            float gy1 = rlane(vg.z, bi), gx1 = rlane(vg.w, bi);              \
            float a2  = rlane(va2,  bi);                                     \
            float ih = fmaxf(fminf(BX.z, gy1) - fmaxf(BX.x, gy0), 0.0f);     \
            float iw = fmaxf(fminf(BX.w, gx1) - fmaxf(BX.y, gx0), 0.0f);     \
            float inter = ih * iw;                                           \
            float s = fmaxf(A1 + a2, 1e-30f);                                \
            float u = inter * __builtin_amdgcn_rcpf(s);                      \
            BEST = (__float_as_uint(u) & 0xFFFFFFC0u) | (uint32_t)(63 - bi); \
        }
        SERIAL(bx0, a10, best0, redo0)
        SERIAL(bx1, a11, best1, redo1)
        #undef SERIAL
    }
    keys[((size_t)b * LL + l0) * SPLIT + sp] = best0;
    if (v1) keys[((size_t)b * LL + l1) * SPLIT + sp] = best1;
}

// ---------------- kernel 1b: cross-split winner + classify (1056 blocks) ---
// Picks the winner with 3 uint max (strict >, lower split keeps on tie).
// Truncated gap > 64 ulp to the other splits -> ONE exact reference-rounded
// IoU+div classifies; else exact 4-way re-merge. Writes u16 cls|midx
// IN-PLACE at the head of this l's own 16-byte key slot.
__global__ __launch_bounds__(256) void merge2_kernel(
    const float* __restrict__ boxes, const float* __restrict__ gt,
    uint32_t* __restrict__ keys)
{
    const int b = blockIdx.y;
    const int l = blockIdx.x * 256 + threadIdx.x;
    if (l >= LL) return;
    const float4* bb4 = (const float4*)(boxes + (size_t)b * NN * 4);
    const float4* gb4 = (const float4*)(gt + (size_t)b * MM * 4);
    const uint4 kv = ((const uint4*)keys)[(size_t)b * LL + l];
    float4 bx = (l < NN) ? bb4[l] : gb4[l - NN];
    int cls, midx = 0;
    uint32_t best = kv.x; int bsp = 0;
    if (kv.y > best) { best = kv.y; bsp = 1; }
    if (kv.z > best) { best = kv.z; bsp = 2; }
    if (kv.w > best) { best = kv.w; bsp = 3; }
    if (fmaxf(fmaxf(bx.x, bx.y), fmaxf(bx.z, bx.w)) < 0.0f) {
        cls = 2;   // invalid box: all sim == -1 -> invalid, argmax = 0
    } else {
        const uint32_t bt = best & ~63u;
        const uint32_t s0 = (bsp == 0) ? 0u : (kv.x & ~63u);
        const uint32_t s1 = (bsp == 1) ? 0u : (kv.y & ~63u);
        const uint32_t s2 = (bsp == 2) ? 0u : (kv.z & ~63u);
        const uint32_t s3 = (bsp == 3) ? 0u : (kv.w & ~63u);
        const uint32_t sec = max(max(s0, s1), max(s2, s3));
        float a1 = (bx.z - bx.x) * (bx.w - bx.y); opaquef(a1);
        if ((bt != 0u) && (bt - sec) <= 64u) {
            // ambiguous across splits: exact 4-way, split ascending, strict >
            float qb = -1.0f; midx = 0;
            #pragma unroll
            for (int sp = 0; sp < SPLIT; ++sp) {
                const uint32_t k = (sp == 0) ? kv.x : (sp == 1) ? kv.y
                                 : (sp == 2) ? kv.z : kv.w;
                const int m = sp * MSUB + (63 - (int)(k & 63u));
                float4 g = gb4[m];
                float a2 = (g.z - g.x) * (g.w - g.y); opaquef(a2);
                float ih = fmaxf(fminf(bx.z, g.z) - fmaxf(bx.x, g.x), 0.0f);
                float iw = fmaxf(fminf(bx.w, g.w) - fmaxf(bx.y, g.y), 0.0f);
                float inter = ih * iw; opaquef(inter);
                float uni = (a1 + a2) - inter;
                float q = (uni > 0.0f) ? (inter / uni) : 0.0f;
                if (q > qb) { qb = q; midx = m; }
            }
            cls = (qb >= 0.5f) ? 1 : 0;
        } else {
            midx = bsp * MSUB + (63 - (int)(best & 63u));
            float4 g = gb4[midx];
            float a2 = (g.z - g.x) * (g.w - g.y); opaquef(a2);
            float ih = fmaxf(fminf(bx.z, g.z) - fmaxf(bx.x, g.x), 0.0f);
            float iw = fmaxf(fminf(bx.w, g.w) - fmaxf(bx.y, g.y), 0.0f);
            float inter = ih * iw; opaquef(inter);
            float uni = (a1 + a2) - inter;     // numpy op order/rounding
            float q = (uni > 0.0f) ? (inter / uni) : 0.0f;   // exact reference
            cls = (q >= 0.5f) ? 1 : 0;         // searchsorted([0,.5,.5], right)
        }
    }
    ((uint16_t*)keys)[((size_t)b * LL + l) * 8] = (uint16_t)(cls | (midx << 2));
}

// ---------------- scans ----------------
__device__ __forceinline__ int block_exscan_fast(int v, int* wt, int tid)
{
    const int lane = tid & 63, w = tid >> 6;
    int x = v;
    #pragma unroll
    for (int off = 1; off < 64; off <<= 1) {
        int y = __shfl_up(x, off);
        if (lane >= off) x += y;
    }
    if (lane == 63) wt[w] = x;
    __syncthreads();
    if (tid < 64) {
        int t = (tid < 16) ? wt[tid] : 0;
        #pragma unroll
        for (int off = 1; off < 16; off <<= 1) {
            int y = __shfl_up(t, off);
            if (tid >= off) t += y;
        }
        if (tid < 16) wt[tid] = t;
    }
    __syncthreads();
    return ((w > 0) ? wt[w - 1] : 0) + x - v;
}

__device__ __forceinline__ int block_exscan_seg4(int v, int* wt, int tid)
{
    const int lane = tid & 63, w = tid >> 6;
    int x = v;
    #pragma unroll
    for (int off = 1; off < 64; off <<= 1) {
        int y = __shfl_up(x, off);
        if (lane >= off) x += y;
    }
    if (lane == 63) wt[w] = x;
    __syncthreads();
    if (tid < 16) {
        int t = wt[tid];
        #pragma unroll
        for (int off = 1; off < 4; off <<= 1) {
            int y = __shfl_up(t, off);
            if ((tid & 3) >= off) t += y;
        }
        wt[tid] = t;
    }
    __syncthreads();
    return (((w & 3) > 0) ? wt[w - 1] : 0) + x - v;
}

// ---------------- kernel 2: per-batch sampling + gather --------------------
// s_pk bit layout: [1:0] cls, [9:2] matched gt idx, [15] sel flag
__global__ __launch_bounds__(T2) void sample_kernel(
    const float* __restrict__ boxes, const float* __restrict__ gt,
    const int* __restrict__ gtc, const float* __restrict__ rnd,
    const uint32_t* __restrict__ keys, float* __restrict__ out)
{
    __shared__ uint32_t s_key[LL];
    __shared__ uint16_t s_pk[LL];
    __shared__ int s_hist[512];
    __shared__ int s_warp[16];
    __shared__ int s_idx[NSAMP];
    __shared__ int s_sb[8];
    const int b = blockIdx.x, tid = threadIdx.x, lane = tid & 63;
    const float4* bb4 = (const float4*)(boxes + (size_t)b * NN * 4);
    const float4* gb4 = (const float4*)(gt + (size_t)b * MM * 4);

    if (tid == 0) s_sb[0] = 0;
    __syncthreads();

    int loc = 0;
    for (int l = tid; l < LL; l += T2) {
        s_key[l] = __float_as_uint(rnd[(size_t)b * LL + l]);
        uint16_t p = ((const uint16_t*)keys)[((size_t)b * LL + l) * 8];
        s_pk[l] = p;
        int c = p & 3;
        loc += (c == 0) ? 1 : ((c == 1) ? 0x10000 : 0);
    }
    #pragma unroll
    for (int off = 32; off; off >>= 1) loc += __shfl_xor(loc, off);
    if (lane == 0) atomicAdd(&s_sb[0], loc);
    __syncthreads();
    const int Nn = s_sb[0] & 0xFFFF, P = s_sb[0] >> 16;

    const int posK = (P < MAXPOS) ? P : MAXPOS;
    const int negK = NSAMP - posK;
    const bool negRad = (Nn > negK);
    const bool posRad = (P > MAXPOS);

    // --- fused dual-class radix select with whole-bin early exit ---
    uint32_t prefix0 = 0, prefix1 = 0;
    int rem0 = negK, rem1 = MAXPOS;
    bool act0 = negRad, act1 = posRad;
    uint32_t thr0f = 0, thr1f = 0;
    int r0f = LL, r1f = LL;
    for (int round = 0; round < 4 && (act0 || act1); ++round) {
        const int shift = 24 - 8 * round;
        if (tid < 512) s_hist[tid] = 0;
        __syncthreads();
        const uint32_t pmask = (round == 0) ? 0u : (0xFFFFFFFFu << (shift + 8));
        for (int l = tid; l < LL; l += T2) {
            const uint32_t k = s_key[l];
            const int c = s_pk[l] & 3;
            bool doit = (c == 0) ? (act0 && ((k & pmask) == prefix0))
                      : (c == 1) ? (act1 && ((k & pmask) == prefix1))
                      : false;
            if (doit) atomicAdd(&s_hist[(c << 8) | ((k >> shift) & 255)], 1);
        }
        __syncthreads();
        int h = 0;
        if (tid < 512) h = s_hist[(tid & 0x100) | (255 - (tid & 255))];
        const int above = block_exscan_seg4(h, s_warp, tid);
        if (tid < 512) {
            const int c = tid >> 8;
            const int rem = c ? rem1 : rem0;
            const bool act = c ? act1 : act0;
            if (act && above < rem && above + h >= rem) {
                s_sb[4 + c * 2] = 255 - (tid & 255);
                s_sb[5 + c * 2] = above;
            }
        }
        __syncthreads();
        if (act0) {
            const int bin = s_sb[4];
            rem0 -= s_sb[5];
            prefix0 |= ((uint32_t)bin) << shift;
            const int cnt = s_hist[bin];
            if (rem0 == cnt)      { act0 = false; thr0f = prefix0; r0f = LL; }
            else if (round == 3)  { act0 = false; thr0f = prefix0; r0f = rem0; }
        }
        if (act1) {
            const int bin = s_sb[6];
            rem1 -= s_sb[7];
            prefix1 |= ((uint32_t)bin) << shift;
            const int cnt = s_hist[256 + bin];
            if (rem1 == cnt)      { act1 = false; thr1f = prefix1; r1f = LL; }
            else if (round == 3)  { act1 = false; thr1f = prefix1; r1f = rem1; }
        }
        __syncthreads();
    }
    const uint32_t thr0 = negRad ? thr0f : 0u;  const int r0 = negRad ? r0f : LL;
    const uint32_t thr1 = posRad ? thr1f : 0u;  const int r1 = posRad ? r1f : LL;

    // --- fused mark pass (tie counts packed: neg low16 | pos high16) ---
    const int lo = tid * CH, hi = (lo + CH < LL) ? (lo + CH) : LL;
    int nt = 0;
    for (int l = lo; l < hi; ++l) {
        const int c = s_pk[l] & 3;
        const uint32_t k = s_key[l];
        if (c == 0) { if (k == thr0) nt += 1; }
        else if (c == 1) { if (k == thr1) nt += 0x10000; }
    }
    const int basep = block_exscan_fast(nt, s_warp, tid);
    int base0 = basep & 0xFFFF, base1 = basep >> 16;
    for (int l = lo; l < hi; ++l) {
        const int c = s_pk[l] & 3;
        if (c > 1) continue;
        const uint32_t k = s_key[l];
        const uint32_t thr = c ? thr1 : thr0;
        bool sel = (k > thr);
        if (k == thr) {
            if (c == 0) { sel = (base0 < r0); ++base0; }
            else        { sel = (base1 < r1); ++base1; }
        }
        if (sel) s_pk[l] |= 0x8000;
    }
    __syncthreads();

    // --- compaction: selected ascending then unselected ascending ---
    int cnt = 0;
    for (int l = lo; l < hi; ++l) cnt += (s_pk[l] & 0x8000) ? 1 : 0x10000;
    const int pb = block_exscan_fast(cnt, s_warp, tid);
    const int S = s_warp[15] & 0xFFFF;
    int bs = pb & 0xFFFF, bu = (pb >> 16) + S;
    for (int l = lo; l < hi; ++l) {
        if (s_pk[l] & 0x8000) { if (bs < NSAMP) s_idx[bs] = l; ++bs; }
        else                  { if (bu < NSAMP) s_idx[bu] = l; ++bu; }
    }
    __syncthreads();

    // --- gather + write all 4 outputs (ints written as float values) ---
    if (tid < NSAMP) {
        const int l = s_idx[tid];
        float4 bx = (l < NN) ? bb4[l] : gb4[l - NN];
        const int p = s_pk[l];
        const int c = p & 3, mi = (p >> 2) & 0xFF;
        const bool bg = (c != 1);          // background = matched_val < 0.5
        float4 gb = make_float4(0.f, 0.f, 0.f, 0.f);
        int cl = 0, si = -1;
        if (!bg) {
            gb = gb4[mi];
            cl = gtc[(size_t)b * MM + mi];
            si = mi;
        }
        const size_t rk = (size_t)b * NSAMP + tid;
        ((float4*)out)[rk] = bx;                                   // rois
        ((float4*)(out + (size_t)BB * NSAMP * 4))[rk] = gb;        // sampled_gt_boxes
        out[(size_t)2 * BB * NSAMP * 4 + rk] = (float)cl;          // classes
        out[(size_t)2 * BB * NSAMP * 4 + (size_t)BB * NSAMP + rk] = (float)si; // indices
    }
}

extern "C" void kernel_launch(void* const* d_in, const int* in_sizes, int n_in,
                              void* d_out, int out_size, void* d_ws, size_t ws_size,
                              hipStream_t stream)
{
    const float* boxes = (const float*)d_in[0];   // [32,8000,4] f32
    const float* gt    = (const float*)d_in[1];   // [32,256,4]  f32
    const int*   gtc   = (const int*)  d_in[2];   // [32,256]    i32
    const float* rnd   = (const float*)d_in[3];   // [32,8256]   f32
    float* out = (float*)d_out;
    uint32_t* keys = (uint32_t*)d_ws;             // BB*LL*SPLIT*4 = 4.22 MB

    dim3 g1((LL + 511) / 512, BB, SPLIT);         // 17,32,4 = 2176 blocks
    match_split_kernel<<<g1, 256, 0, stream>>>(boxes, gt, keys);
    dim3 g2((LL + 255) / 256, BB);                // 33,32
    merge2_kernel<<<g2, 256, 0, stream>>>(boxes, gt, keys);
    sample_kernel<<<BB, T2, 0, stream>>>(boxes, gt, gtc, rnd, keys, out);
}

// Round 17
// 71.583 us; speedup vs baseline: 1.1919x; 1.1919x over previous
//
#include <hip/hip_runtime.h>
#include <stdint.h>

#define BB 32
#define NN 8000
#define MM 256
#define LL (NN + MM)        // 8256
#define NSAMP 512
#define MAXPOS 128
#define T2 1024
#define CH ((LL + T2 - 1) / T2)   // 9
#define SPLIT 4
#define MSUB (MM / SPLIT)   // 64
#define ONE_P 1.0000019073486328f   // 1 + 2^-19 (exact in f32)
#define ONE_M 0.9999980926513672f   // 1 - 2^-19 (exact in f32)

// forbid fp-contract across this value (match numpy rounding); NON-volatile
__device__ __forceinline__ void opaquef(float& x) { asm("" : "+v"(x)); }

// exact reference semantics within one split (serial, IEEE div) -- rare
__device__ __noinline__ void serial_argmax_q(const float4 bx, const float a1,
                                             const float4* s_gt, const float* s_a2,
                                             int* obi, float* oq)
{
    float qb = -1.0f; int bi = 0;
    for (int m = 0; m < MSUB; ++m) {
        float4 g = s_gt[m];
        float ih = fmaxf(fminf(bx.z, g.z) - fmaxf(bx.x, g.x), 0.0f);
        float iw = fmaxf(fminf(bx.w, g.w) - fmaxf(bx.y, g.y), 0.0f);
        float inter = ih * iw; opaquef(inter);
        float uni = (a1 + s_a2[m]) - inter;        // numpy op order/rounding
        float q = (uni > 0.0f) ? (inter / uni) : 0.0f;
        if (q > qb) { qb = q; bi = m; }
    }
    *obi = bi; *oq = qb;
}

// ---------------- kernel 1: per-(b, box-pair, split) argmax + exact-q key --
// R6 structure verbatim (best measured match, 41.8us: cross-mult margin
// compare, 2 chains/box, 2 boxes/thread, SPLIT=4): with s = fl(a1+a2),
// exact identity i/(s-i) > j/(t-j) <=> i*t > j*s. p1 > p2*(1+2^-19) ->
// rounded quotients (the reference compares those) strictly ordered: WIN;
// p1 <= p2*(1-2^-19) -> LOSE; between (covers all exact ties) -> exact
// serial redo. NEW TAIL (replaces merge2 kernel): the split winner's EXACT
// reference-rounded q from the tracked (inter, s) pair -- uni = fl(s-inter),
// q = fl(inter/uni), identical operands+rounding as the reference -- stored
// as key = (q_bits & ~63) | (63 - m). Since q is exact:
//   - trunc(q) >= 0x3F000000 <=> q >= 0.5 EXACTLY (trunc only clears bits
//     below the boundary), so classification downstream is free;
//   - cross-split trunc gap >= 1 step guarantees strict exact-q order;
//     equal truncs (incl. all-zero rows) -> rare exact re-merge in sample.
// Zero-overlap rows: winner is always m=0 (strict-win never fires), q=0,
// key = 63 != 0. Invalid boxes write key 0 (unique marker).
__global__ __launch_bounds__(256) void match_split_kernel(
    const float* __restrict__ boxes, const float* __restrict__ gt,
    uint32_t* __restrict__ keys)
{
    __shared__ float4 s_gt[MSUB];
    __shared__ float  s_a2[MSUB];
    const int b = blockIdx.y, sp = blockIdx.z, tid = threadIdx.x;
    if (tid < MSUB) {
        float4 v = ((const float4*)(gt + ((size_t)b * MM + sp * MSUB) * 4))[tid];
        s_gt[tid] = v;
        s_a2[tid] = (v.z - v.x) * (v.w - v.y);   // invalid gt (-1,...) -> 0
    }
    __syncthreads();
    const int l0 = blockIdx.x * 512 + tid * 2;
    if (l0 >= LL) return;
    const int l1 = l0 + 1;
    const bool v1 = (l1 < LL);
    const int l1c = v1 ? l1 : l0;

    const float4* bb4 = (const float4*)(boxes + (size_t)b * NN * 4);
    const float4* gb4 = (const float4*)(gt + (size_t)b * MM * 4);
    float4 bx0 = (l0 < NN) ? bb4[l0] : gb4[l0 - NN];
    float4 bx1 = (l1c < NN) ? bb4[l1c] : gb4[l1c - NN];
    float a10 = (bx0.z - bx0.x) * (bx0.w - bx0.y); opaquef(a10);
    float a11 = (bx1.z - bx1.x) * (bx1.w - bx1.y); opaquef(a11);
    const bool binv0 = fmaxf(fmaxf(bx0.x, bx0.y), fmaxf(bx0.z, bx0.w)) < 0.0f;
    const bool binv1 = fmaxf(fmaxf(bx1.x, bx1.y), fmaxf(bx1.z, bx1.w)) < 0.0f;

    // 2 independent chains per box (even/odd m) for ILP; branchless updates
    float I00 = 0.f, S00 = 1.f, I01 = 0.f, S01 = 1.f;
    float I10 = 0.f, S10 = 1.f, I11 = 0.f, S11 = 1.f;
    int X00 = 0, X01 = 1, X10 = 0, X11 = 1;
    bool redo0 = false, redo1 = false;

    #define STEP(BX, A1, G, A2, BI, BS, BIX, MIDX, RD)                       \
    {                                                                        \
        float ih = fmaxf(fminf(BX.z, G.z) - fmaxf(BX.x, G.x), 0.0f);         \
        float iw = fmaxf(fminf(BX.w, G.w) - fmaxf(BX.y, G.y), 0.0f);         \
        float inter = ih * iw; opaquef(inter);                               \
        float s  = A1 + A2;                                                  \
        float p1 = inter * BS, p2 = BI * s;                                  \
        bool win = p1 > p2 * ONE_P;                                          \
        RD |= ((p1 > p2 * ONE_M) != win);                                    \
        if (win) { BI = inter; BS = s; BIX = MIDX; }                         \
    }
    #pragma unroll 4
    for (int m = 0; m < MSUB; m += 2) {
        float4 g0 = s_gt[m];     float a2_0 = s_a2[m];
        float4 g1 = s_gt[m + 1]; float a2_1 = s_a2[m + 1];
        STEP(bx0, a10, g0, a2_0, I00, S00, X00, m,     redo0)
        STEP(bx0, a10, g1, a2_1, I01, S01, X01, m + 1, redo0)
        STEP(bx1, a11, g0, a2_0, I10, S10, X10, m,     redo1)
        STEP(bx1, a11, g1, a2_1, I11, S11, X11, m + 1, redo1)
    }
    #undef STEP

    // merge odd chain into even: adopt only on strict win; any closeness
    // (incl. exact ties, where odd may hold the LOWER index) -> redo
    #define MERGE(I0, S0, X0, I1, S1, X1, RD)                                \
    {                                                                        \
        float p1 = I1 * S0, p2 = I0 * S1;                                    \
        bool win = p1 > p2 * ONE_P;                                          \
        RD |= ((p1 > p2 * ONE_M) != win);                                    \
        if (win) { I0 = I1; S0 = S1; X0 = X1; }                              \
    }
    MERGE(I00, S00, X00, I01, S01, X01, redo0)
    MERGE(I10, S10, X10, I11, S11, X11, redo1)
    #undef MERGE

    float q0, q1; int m0 = X00, m1 = X10;
    if (__any(redo0 || redo1)) {
        if (redo0) serial_argmax_q(bx0, a10, s_gt, s_a2, &m0, &q0);
        if (redo1) serial_argmax_q(bx1, a11, s_gt, s_a2, &m1, &q1);
    }
    if (!redo0) {
        float uni = S00 - I00;                     // = fl(fl(a1+a2) - inter)
        q0 = (uni > 0.0f) ? (I00 / uni) : 0.0f;    // exact reference rounding
    }
    if (!redo1) {
        float uni = S10 - I10;
        q1 = (uni > 0.0f) ? (I10 / uni) : 0.0f;
    }
    uint32_t k0 = binv0 ? 0u
        : ((__float_as_uint(q0) & 0xFFFFFFC0u) | (uint32_t)(63 - m0));
    keys[((size_t)b * LL + l0) * SPLIT + sp] = k0;
    if (v1) {
        uint32_t k1 = binv1 ? 0u
            : ((__float_as_uint(q1) & 0xFFFFFFC0u) | (uint32_t)(63 - m1));
        keys[((size_t)b * LL + l1) * SPLIT + sp] = k1;
    }
}

// ---------------- scans ----------------
__device__ __forceinline__ int block_exscan_fast(int v, int* wt, int tid)
{
    const int lane = tid & 63, w = tid >> 6;
    int x = v;
    #pragma unroll
    for (int off = 1; off < 64; off <<= 1) {
        int y = __shfl_up(x, off);
        if (lane >= off) x += y;
    }
    if (lane == 63) wt[w] = x;
    __syncthreads();
    if (tid < 64) {
        int t = (tid < 16) ? wt[tid] : 0;
        #pragma unroll
        for (int off = 1; off < 16; off <<= 1) {
            int y = __shfl_up(t, off);
            if (tid >= off) t += y;
        }
        if (tid < 16) wt[tid] = t;
    }
    __syncthreads();
    return ((w > 0) ? wt[w - 1] : 0) + x - v;
}

__device__ __forceinline__ int block_exscan_seg4(int v, int* wt, int tid)
{
    const int lane = tid & 63, w = tid >> 6;
    int x = v;
    #pragma unroll
    for (int off = 1; off < 64; off <<= 1) {
        int y = __shfl_up(x, off);
        if (lane >= off) x += y;
    }
    if (lane == 63) wt[w] = x;
    __syncthreads();
    if (tid < 16) {
        int t = wt[tid];
        #pragma unroll
        for (int off = 1; off < 4; off <<= 1) {
            int y = __shfl_up(t, off);
            if ((tid & 3) >= off) t += y;
        }
        wt[tid] = t;
    }
    __syncthreads();
    return (((w & 3) > 0) ? wt[w - 1] : 0) + x - v;
}

// ---------------- kernel 2: merge-decode + per-batch sampling + gather -----
// s_pk bit layout: [1:0] cls, [9:2] matched gt idx, [15] sel flag
__global__ __launch_bounds__(T2) void sample_kernel(
    const float* __restrict__ boxes, const float* __restrict__ gt,
    const int* __restrict__ gtc, const float* __restrict__ rnd,
    const uint32_t* __restrict__ keys, float* __restrict__ out)
{
    __shared__ uint32_t s_key[LL];
    __shared__ uint16_t s_pk[LL];
    __shared__ int s_hist[512];
    __shared__ int s_warp[16];
    __shared__ int s_idx[NSAMP];
    __shared__ int s_sb[8];
    const int b = blockIdx.x, tid = threadIdx.x, lane = tid & 63;
    const float4* bb4 = (const float4*)(boxes + (size_t)b * NN * 4);
    const float4* gb4 = (const float4*)(gt + (size_t)b * MM * 4);

    if (tid == 0) s_sb[0] = 0;
    __syncthreads();

    // load rand keys + cross-split merge decode (3 uint max; exact-q keys:
    // bt > sec guarantees strict exact order; bt == sec -> rare exact
    // 4-way re-merge) + packed class counts (neg lo16 | pos hi16)
    int loc = 0;
    for (int l = tid; l < LL; l += T2) {
        s_key[l] = __float_as_uint(rnd[(size_t)b * LL + l]);
        const uint4 kv = ((const uint4*)keys)[(size_t)b * LL + l];
        uint32_t best = kv.x; int bsp = 0;
        if (kv.y > best) { best = kv.y; bsp = 1; }
        if (kv.z > best) { best = kv.z; bsp = 2; }
        if (kv.w > best) { best = kv.w; bsp = 3; }
        uint16_t p;
        if (best == 0u) {
            p = 2;    // invalid box: all sim == -1 -> cls invalid, argmax 0
        } else {
            const uint32_t bt = best & ~63u;
            const uint32_t e0 = (bsp == 0) ? 0u : (kv.x & ~63u);
            const uint32_t e1 = (bsp == 1) ? 0u : (kv.y & ~63u);
            const uint32_t e2 = (bsp == 2) ? 0u : (kv.z & ~63u);
            const uint32_t e3 = (bsp == 3) ? 0u : (kv.w & ~63u);
            const uint32_t sec = max(max(e0, e1), max(e2, e3));
            int cls, midx;
            if (bt > sec) {
                midx = bsp * MSUB + (63 - (int)(best & 63u));
                cls = (bt >= 0x3F000000u) ? 1 : 0;   // exact: q >= 0.5
            } else {
                // exact 4-way re-merge (rare: equal trunc-q across splits,
                // incl. all-zero rows); split ascending, strict > = global
                // first-argmax over the reference's rounded q
                float4 bx = (l < NN) ? bb4[l] : gb4[l - NN];
                float a1 = (bx.z - bx.x) * (bx.w - bx.y); opaquef(a1);
                float qb = -1.0f; midx = 0;
                #pragma unroll
                for (int sp = 0; sp < SPLIT; ++sp) {
                    const uint32_t k = (sp == 0) ? kv.x : (sp == 1) ? kv.y
                                     : (sp == 2) ? kv.z : kv.w;
                    if (k == 0u) continue;
                    const int m = sp * MSUB + (63 - (int)(k & 63u));
                    float4 g = gb4[m];
                    float a2 = (g.z - g.x) * (g.w - g.y); opaquef(a2);
                    float ih = fmaxf(fminf(bx.z, g.z) - fmaxf(bx.x, g.x), 0.0f);
                    float iw = fmaxf(fminf(bx.w, g.w) - fmaxf(bx.y, g.y), 0.0f);
                    float inter = ih * iw; opaquef(inter);
                    float uni = (a1 + a2) - inter;
                    float q = (uni > 0.0f) ? (inter / uni) : 0.0f;
                    if (q > qb) { qb = q; midx = m; }
                }
                cls = (qb >= 0.5f) ? 1 : 0;
            }
            p = (uint16_t)(cls | (midx << 2));
        }
        s_pk[l] = p;
        int c = p & 3;
        loc += (c == 0) ? 1 : ((c == 1) ? 0x10000 : 0);
    }
    #pragma unroll
    for (int off = 32; off; off >>= 1) loc += __shfl_xor(loc, off);
    if (lane == 0) atomicAdd(&s_sb[0], loc);
    __syncthreads();
    const int Nn = s_sb[0] & 0xFFFF, P = s_sb[0] >> 16;

    const int posK = (P < MAXPOS) ? P : MAXPOS;
    const int negK = NSAMP - posK;
    const bool negRad = (Nn > negK);
    const bool posRad = (P > MAXPOS);

    // --- fused dual-class radix select with whole-bin early exit ---
    uint32_t prefix0 = 0, prefix1 = 0;
    int rem0 = negK, rem1 = MAXPOS;
    bool act0 = negRad, act1 = posRad;
    uint32_t thr0f = 0, thr1f = 0;
    int r0f = LL, r1f = LL;
    for (int round = 0; round < 4 && (act0 || act1); ++round) {
        const int shift = 24 - 8 * round;
        if (tid < 512) s_hist[tid] = 0;
        __syncthreads();
        const uint32_t pmask = (round == 0) ? 0u : (0xFFFFFFFFu << (shift + 8));
        for (int l = tid; l < LL; l += T2) {
            const uint32_t k = s_key[l];
            const int c = s_pk[l] & 3;
            bool doit = (c == 0) ? (act0 && ((k & pmask) == prefix0))
                      : (c == 1) ? (act1 && ((k & pmask) == prefix1))
                      : false;
            if (doit) atomicAdd(&s_hist[(c << 8) | ((k >> shift) & 255)], 1);
        }
        __syncthreads();
        int h = 0;
        if (tid < 512) h = s_hist[(tid & 0x100) | (255 - (tid & 255))];
        const int above = block_exscan_seg4(h, s_warp, tid);
        if (tid < 512) {
            const int c = tid >> 8;
            const int rem = c ? rem1 : rem0;
            const bool act = c ? act1 : act0;
            if (act && above < rem && above + h >= rem) {
                s_sb[4 + c * 2] = 255 - (tid & 255);
                s_sb[5 + c * 2] = above;
            }
        }
        __syncthreads();
        if (act0) {
            const int bin = s_sb[4];
            rem0 -= s_sb[5];
            prefix0 |= ((uint32_t)bin) << shift;
            const int cnt = s_hist[bin];
            if (rem0 == cnt)      { act0 = false; thr0f = prefix0; r0f = LL; }
            else if (round == 3)  { act0 = false; thr0f = prefix0; r0f = rem0; }
        }
        if (act1) {
            const int bin = s_sb[6];
            rem1 -= s_sb[7];
            prefix1 |= ((uint32_t)bin) << shift;
            const int cnt = s_hist[256 + bin];
            if (rem1 == cnt)      { act1 = false; thr1f = prefix1; r1f = LL; }
            else if (round == 3)  { act1 = false; thr1f = prefix1; r1f = rem1; }
        }
        __syncthreads();
    }
    const uint32_t thr0 = negRad ? thr0f : 0u;  const int r0 = negRad ? r0f : LL;
    const uint32_t thr1 = posRad ? thr1f : 0u;  const int r1 = posRad ? r1f : LL;

    // --- fused mark pass (tie counts packed: neg low16 | pos high16) ---
    const int lo = tid * CH, hi = (lo + CH < LL) ? (lo + CH) : LL;
    int nt = 0;
    for (int l = lo; l < hi; ++l) {
        const int c = s_pk[l] & 3;
        const uint32_t k = s_key[l];
        if (c == 0) { if (k == thr0) nt += 1; }
        else if (c == 1) { if (k == thr1) nt += 0x10000; }
    }
    const int basep = block_exscan_fast(nt, s_warp, tid);
    int base0 = basep & 0xFFFF, base1 = basep >> 16;
    for (int l = lo; l < hi; ++l) {
        const int c = s_pk[l] & 3;
        if (c > 1) continue;
        const uint32_t k = s_key[l];
        const uint32_t thr = c ? thr1 : thr0;
        bool sel = (k > thr);
        if (k == thr) {
            if (c == 0) { sel = (base0 < r0); ++base0; }
            else        { sel = (base1 < r1); ++base1; }
        }
        if (sel) s_pk[l] |= 0x8000;
    }
    __syncthreads();

    // --- compaction: selected ascending then unselected ascending ---
    int cnt = 0;
    for (int l = lo; l < hi; ++l) cnt += (s_pk[l] & 0x8000) ? 1 : 0x10000;
    const int pb = block_exscan_fast(cnt, s_warp, tid);
    const int S = s_warp[15] & 0xFFFF;
    int bs = pb & 0xFFFF, bu = (pb >> 16) + S;
    for (int l = lo; l < hi; ++l) {
        if (s_pk[l] & 0x8000) { if (bs < NSAMP) s_idx[bs] = l; ++bs; }
        else                  { if (bu < NSAMP) s_idx[bu] = l; ++bu; }
    }
    __syncthreads();

    // --- gather + write all 4 outputs (ints written as float values) ---
    if (tid < NSAMP) {
        const int l = s_idx[tid];
        float4 bx = (l < NN) ? bb4[l] : gb4[l - NN];
        const int p = s_pk[l];
        const int c = p & 3, mi = (p >> 2) & 0xFF;
        const bool bg = (c != 1);          // background = matched_val < 0.5
        float4 gb = make_float4(0.f, 0.f, 0.f, 0.f);
        int cl = 0, si = -1;
        if (!bg) {
            gb = gb4[mi];
            cl = gtc[(size_t)b * MM + mi];
            si = mi;
        }
        const size_t rk = (size_t)b * NSAMP + tid;
        ((float4*)out)[rk] = bx;                                   // rois
        ((float4*)(out + (size_t)BB * NSAMP * 4))[rk] = gb;        // sampled_gt_boxes
        out[(size_t)2 * BB * NSAMP * 4 + rk] = (float)cl;          // classes
        out[(size_t)2 * BB * NSAMP * 4 + (size_t)BB * NSAMP + rk] = (float)si; // indices
    }
}

extern "C" void kernel_launch(void* const* d_in, const int* in_sizes, int n_in,
                              void* d_out, int out_size, void* d_ws, size_t ws_size,
                              hipStream_t stream)
{
    const float* boxes = (const float*)d_in[0];   // [32,8000,4] f32
    const float* gt    = (const float*)d_in[1];   // [32,256,4]  f32
    const int*   gtc   = (const int*)  d_in[2];   // [32,256]    i32
    const float* rnd   = (const float*)d_in[3];   // [32,8256]   f32
    float* out = (float*)d_out;
    uint32_t* keys = (uint32_t*)d_ws;             // BB*LL*SPLIT*4 = 4.22 MB

    dim3 g1((LL + 511) / 512, BB, SPLIT);         // 17,32,4 = 2176 blocks (R6)
    match_split_kernel<<<g1, 256, 0, stream>>>(boxes, gt, keys);
    sample_kernel<<<BB, T2, 0, stream>>>(boxes, gt, gtc, rnd, keys, out);
}

// Round 18
// 68.016 us; speedup vs baseline: 1.2544x; 1.0524x over previous
//
#include <hip/hip_runtime.h>
#include <stdint.h>

#define BB 32
#define NN 8000
#define MM 256
#define LL (NN + MM)        // 8256
#define NSAMP 512
#define MAXPOS 128
#define T2 1024
#define CH ((LL + T2 - 1) / T2)   // 9
#define SPLIT 4
#define MSUB (MM / SPLIT)   // 64
#define ONE_P 1.0000019073486328f   // 1 + 2^-19 (exact in f32)
#define ONE_M 0.9999980926513672f   // 1 - 2^-19 (exact in f32)

// forbid fp-contract across this value (match numpy rounding); NON-volatile
__device__ __forceinline__ void opaquef(float& x) { asm("" : "+v"(x)); }

// exact reference semantics within one split (serial, IEEE div) -- rare
__device__ __noinline__ int serial_argmax(const float4 bx, const float a1,
                                          const float4* s_gt, const float* s_a2)
{
    float qb = -1.0f; int bi = 0;
    for (int m = 0; m < MSUB; ++m) {
        float4 g = s_gt[m];
        float ih = fmaxf(fminf(bx.z, g.z) - fmaxf(bx.x, g.x), 0.0f);
        float iw = fmaxf(fminf(bx.w, g.w) - fmaxf(bx.y, g.y), 0.0f);
        float inter = ih * iw; opaquef(inter);
        float uni = (a1 + s_a2[m]) - inter;        // numpy op order/rounding
        float q = (uni > 0.0f) ? (inter / uni) : 0.0f;
        if (q > qb) { qb = q; bi = m; }
    }
    return bi;
}

// ---------------- kernel 1: per-(b, box-pair, split) argmax over 64 gts ----
// BEST MEASURED MATCH (41.8us, R5): with s = fl(a1+a2), exact identity
// i/(s-i) > j/(t-j) <=> i*t > j*s. Decision: p1 > p2*(1+2^-19) -> rounded
// quotients (the reference compares those) strictly ordered: WIN;
// p1 <= p2*(1-2^-19) -> LOSE; between (covers all exact ties and the
// boundary) -> exact serial redo with IEEE division (bit-identical to the
// reference compare). Invalid (-1) boxes/gts give inter = 0 -> never win,
// never ambiguous -> running index stays 0, matching the reference argmax
// for all -1 rows. 2 boxes/thread amortize the LDS broadcast reads.
__global__ __launch_bounds__(256) void match_split_kernel(
    const float* __restrict__ boxes, const float* __restrict__ gt,
    uint8_t* __restrict__ pidx)
{
    __shared__ float4 s_gt[MSUB];
    __shared__ float  s_a2[MSUB];
    const int b = blockIdx.y, sp = blockIdx.z, tid = threadIdx.x;
    if (tid < MSUB) {
        float4 v = ((const float4*)(gt + ((size_t)b * MM + sp * MSUB) * 4))[tid];
        s_gt[tid] = v;
        s_a2[tid] = (v.z - v.x) * (v.w - v.y);   // invalid gt (-1,...) -> 0
    }
    __syncthreads();
    const int l0 = blockIdx.x * 512 + tid * 2;
    if (l0 >= LL) return;
    const int l1 = l0 + 1;
    const bool v1 = (l1 < LL);
    const int l1c = v1 ? l1 : l0;

    const float4* bb4 = (const float4*)(boxes + (size_t)b * NN * 4);
    const float4* gb4 = (const float4*)(gt + (size_t)b * MM * 4);
    float4 bx0 = (l0 < NN) ? bb4[l0] : gb4[l0 - NN];
    float4 bx1 = (l1c < NN) ? bb4[l1c] : gb4[l1c - NN];

    float a10 = (bx0.z - bx0.x) * (bx0.w - bx0.y); opaquef(a10);
    float a11 = (bx1.z - bx1.x) * (bx1.w - bx1.y); opaquef(a11);

    // 2 independent chains per box (even/odd m) for ILP; branchless updates
    float I00 = 0.f, S00 = 1.f, I01 = 0.f, S01 = 1.f;
    float I10 = 0.f, S10 = 1.f, I11 = 0.f, S11 = 1.f;
    int X00 = 0, X01 = 1, X10 = 0, X11 = 1;
    bool redo0 = false, redo1 = false;

    #define STEP(BX, A1, G, A2, BI, BS, BIX, MIDX, RD)                       \
    {                                                                        \
        float ih = fmaxf(fminf(BX.z, G.z) - fmaxf(BX.x, G.x), 0.0f);         \
        float iw = fmaxf(fminf(BX.w, G.w) - fmaxf(BX.y, G.y), 0.0f);         \
        float inter = ih * iw; opaquef(inter);                               \
        float s  = A1 + A2;                                                  \
        float p1 = inter * BS, p2 = BI * s;                                  \
        bool win = p1 > p2 * ONE_P;                                          \
        RD |= ((p1 > p2 * ONE_M) != win);                                    \
        if (win) { BI = inter; BS = s; BIX = MIDX; }                         \
    }
    #pragma unroll 4
    for (int m = 0; m < MSUB; m += 2) {
        float4 g0 = s_gt[m];     float a2_0 = s_a2[m];
        float4 g1 = s_gt[m + 1]; float a2_1 = s_a2[m + 1];
        STEP(bx0, a10, g0, a2_0, I00, S00, X00, m,     redo0)
        STEP(bx0, a10, g1, a2_1, I01, S01, X01, m + 1, redo0)
        STEP(bx1, a11, g0, a2_0, I10, S10, X10, m,     redo1)
        STEP(bx1, a11, g1, a2_1, I11, S11, X11, m + 1, redo1)
    }
    #undef STEP

    // merge odd chain into even: adopt only on strict win; any closeness
    // (incl. exact ties, where odd may hold the LOWER index) -> redo
    #define MERGE(I0, S0, X0, I1, S1, X1, RD)                                \
    {                                                                        \
        float p1 = I1 * S0, p2 = I0 * S1;                                    \
        bool win = p1 > p2 * ONE_P;                                          \
        RD |= ((p1 > p2 * ONE_M) != win);                                    \
        if (win) { X0 = X1; }                                                \
    }
    MERGE(I00, S00, X00, I01, S01, X01, redo0)
    MERGE(I10, S10, X10, I11, S11, X11, redo1)
    #undef MERGE

    int lb0 = X00, lb1 = X10;
    if (__any(redo0 || redo1)) {
        if (redo0) lb0 = serial_argmax(bx0, a10, s_gt, s_a2);
        if (redo1) lb1 = serial_argmax(bx1, a11, s_gt, s_a2);
    }
    pidx[((size_t)b * LL + l0) * SPLIT + sp] = (uint8_t)lb0;
    if (v1) pidx[((size_t)b * LL + l1) * SPLIT + sp] = (uint8_t)lb1;
}

// ---------------- kernel 1b: merge 4 split winners, exact rounded q --------
// 1056 blocks. Exact 4-way re-merge (reference op order/rounding, IEEE div);
// split ascending + strict > = global first-argmax. Classify via q >= 0.5.
__global__ __launch_bounds__(256) void merge_kernel(
    const float* __restrict__ boxes, const float* __restrict__ gt,
    const uint8_t* __restrict__ pidx, uint16_t* __restrict__ packed)
{
    const int b = blockIdx.y;
    const int l = blockIdx.x * 256 + threadIdx.x;
    if (l >= LL) return;
    float4 bx = (l < NN) ? ((const float4*)(boxes + (size_t)b * NN * 4))[l]
                         : ((const float4*)(gt + (size_t)b * MM * 4))[l - NN];
    int cls, bidx = 0;
    if (fmaxf(fmaxf(bx.x, bx.y), fmaxf(bx.z, bx.w)) < 0.0f) {
        cls = 2;   // invalid box: all sim == -1 -> invalid, argmax = 0
    } else {
        float a1 = (bx.z - bx.x) * (bx.w - bx.y); opaquef(a1);
        float qb = -1.0f;
        const uint32_t pv = *(const uint32_t*)&pidx[((size_t)b * LL + l) * SPLIT];
        #pragma unroll
        for (int sp = 0; sp < SPLIT; ++sp) {
            const int m = sp * MSUB + (int)((pv >> (8 * sp)) & 0xFFu);
            float4 g = ((const float4*)(gt + (size_t)b * MM * 4))[m];
            float a2 = (g.z - g.x) * (g.w - g.y); opaquef(a2);
            float ih = fmaxf(fminf(bx.z, g.z) - fmaxf(bx.x, g.x), 0.0f);
            float iw = fmaxf(fminf(bx.w, g.w) - fmaxf(bx.y, g.y), 0.0f);
            float inter = ih * iw; opaquef(inter);
            float uni = (a1 + a2) - inter;        // numpy op order/rounding
            float q = (uni > 0.0f) ? (inter / uni) : 0.0f;   // exact reference
            if (q > qb) { qb = q; bidx = m; }     // split order = index order
        }
        cls = (qb >= 0.5f) ? 1 : 0;   // searchsorted([0,.5,.5], right)
    }
    packed[(size_t)b * LL + l] = (uint16_t)(cls | (bidx << 2));
}

// ---------------- scans ----------------
__device__ __forceinline__ int block_exscan_fast(int v, int* wt, int tid)
{
    const int lane = tid & 63, w = tid >> 6;
    int x = v;
    #pragma unroll
    for (int off = 1; off < 64; off <<= 1) {
        int y = __shfl_up(x, off);
        if (lane >= off) x += y;
    }
    if (lane == 63) wt[w] = x;
    __syncthreads();
    if (tid < 64) {
        int t = (tid < 16) ? wt[tid] : 0;
        #pragma unroll
        for (int off = 1; off < 16; off <<= 1) {
            int y = __shfl_up(t, off);
            if (tid >= off) t += y;
        }
        if (tid < 16) wt[tid] = t;
    }
    __syncthreads();
    return ((w > 0) ? wt[w - 1] : 0) + x - v;
}

__device__ __forceinline__ int block_exscan_seg4(int v, int* wt, int tid)
{
    const int lane = tid & 63, w = tid >> 6;
    int x = v;
    #pragma unroll
    for (int off = 1; off < 64; off <<= 1) {
        int y = __shfl_up(x, off);
        if (lane >= off) x += y;
    }
    if (lane == 63) wt[w] = x;
    __syncthreads();
    if (tid < 16) {
        int t = wt[tid];
        #pragma unroll
        for (int off = 1; off < 4; off <<= 1) {
            int y = __shfl_up(t, off);
            if ((tid & 3) >= off) t += y;
        }
        wt[tid] = t;
    }
    __syncthreads();
    return (((w & 3) > 0) ? wt[w - 1] : 0) + x - v;
}

// ---------------- kernel 2: per-batch sampling + gather --------------------
// s_pk bit layout: [1:0] cls, [9:2] matched gt idx, [15] sel flag
__global__ __launch_bounds__(T2) void sample_kernel(
    const float* __restrict__ boxes, const float* __restrict__ gt,
    const int* __restrict__ gtc, const float* __restrict__ rnd,
    const uint16_t* __restrict__ packed, float* __restrict__ out)
{
    __shared__ uint32_t s_key[LL];
    __shared__ uint16_t s_pk[LL];
    __shared__ int s_hist[512];
    __shared__ int s_warp[16];
    __shared__ int s_idx[NSAMP];
    __shared__ int s_sb[8];
    const int b = blockIdx.x, tid = threadIdx.x, lane = tid & 63;
    const float4* bb4 = (const float4*)(boxes + (size_t)b * NN * 4);
    const float4* gb4 = (const float4*)(gt + (size_t)b * MM * 4);

    if (tid == 0) s_sb[0] = 0;
    __syncthreads();

    int loc = 0;
    for (int l = tid; l < LL; l += T2) {
        s_key[l] = __float_as_uint(rnd[(size_t)b * LL + l]);
        uint16_t p = packed[(size_t)b * LL + l];
        s_pk[l] = p;
        int c = p & 3;
        loc += (c == 0) ? 1 : ((c == 1) ? 0x10000 : 0);
    }
    #pragma unroll
    for (int off = 32; off; off >>= 1) loc += __shfl_xor(loc, off);
    if (lane == 0) atomicAdd(&s_sb[0], loc);
    __syncthreads();
    const int Nn = s_sb[0] & 0xFFFF, P = s_sb[0] >> 16;

    const int posK = (P < MAXPOS) ? P : MAXPOS;
    const int negK = NSAMP - posK;
    const bool negRad = (Nn > negK);
    const bool posRad = (P > MAXPOS);

    // --- fused dual-class radix select with whole-bin early exit ---
    uint32_t prefix0 = 0, prefix1 = 0;
    int rem0 = negK, rem1 = MAXPOS;
    bool act0 = negRad, act1 = posRad;
    uint32_t thr0f = 0, thr1f = 0;
    int r0f = LL, r1f = LL;
    for (int round = 0; round < 4 && (act0 || act1); ++round) {
        const int shift = 24 - 8 * round;
        if (tid < 512) s_hist[tid] = 0;
        __syncthreads();
        const uint32_t pmask = (round == 0) ? 0u : (0xFFFFFFFFu << (shift + 8));
        for (int l = tid; l < LL; l += T2) {
            const uint32_t k = s_key[l];
            const int c = s_pk[l] & 3;
            bool doit = (c == 0) ? (act0 && ((k & pmask) == prefix0))
                      : (c == 1) ? (act1 && ((k & pmask) == prefix1))
                      : false;
            if (doit) atomicAdd(&s_hist[(c << 8) | ((k >> shift) & 255)], 1);
        }
        __syncthreads();
        int h = 0;
        if (tid < 512) h = s_hist[(tid & 0x100) | (255 - (tid & 255))];
        const int above = block_exscan_seg4(h, s_warp, tid);
        if (tid < 512) {
            const int c = tid >> 8;
            const int rem = c ? rem1 : rem0;
            const bool act = c ? act1 : act0;
            if (act && above < rem && above + h >= rem) {
                s_sb[4 + c * 2] = 255 - (tid & 255);
                s_sb[5 + c * 2] = above;
            }
        }
        __syncthreads();
        if (act0) {
            const int bin = s_sb[4];
            rem0 -= s_sb[5];
            prefix0 |= ((uint32_t)bin) << shift;
            const int cnt = s_hist[bin];
            if (rem0 == cnt)      { act0 = false; thr0f = prefix0; r0f = LL; }
            else if (round == 3)  { act0 = false; thr0f = prefix0; r0f = rem0; }
        }
        if (act1) {
            const int bin = s_sb[6];
            rem1 -= s_sb[7];
            prefix1 |= ((uint32_t)bin) << shift;
            const int cnt = s_hist[256 + bin];
            if (rem1 == cnt)      { act1 = false; thr1f = prefix1; r1f = LL; }
            else if (round == 3)  { act1 = false; thr1f = prefix1; r1f = rem1; }
        }
        __syncthreads();
    }
    const uint32_t thr0 = negRad ? thr0f : 0u;  const int r0 = negRad ? r0f : LL;
    const uint32_t thr1 = posRad ? thr1f : 0u;  const int r1 = posRad ? r1f : LL;

    // --- fused mark pass (tie counts packed: neg low16 | pos high16) ---
    const int lo = tid * CH, hi = (lo + CH < LL) ? (lo + CH) : LL;
    int nt = 0;
    for (int l = lo; l < hi; ++l) {
        const int c = s_pk[l] & 3;
        const uint32_t k = s_key[l];
        if (c == 0) { if (k == thr0) nt += 1; }
        else if (c == 1) { if (k == thr1) nt += 0x10000; }
    }
    const int basep = block_exscan_fast(nt, s_warp, tid);
    int base0 = basep & 0xFFFF, base1 = basep >> 16;
    for (int l = lo; l < hi; ++l) {
        const int c = s_pk[l] & 3;
        if (c > 1) continue;
        const uint32_t k = s_key[l];
        const uint32_t thr = c ? thr1 : thr0;
        bool sel = (k > thr);
        if (k == thr) {
            if (c == 0) { sel = (base0 < r0); ++base0; }
            else        { sel = (base1 < r1); ++base1; }
        }
        if (sel) s_pk[l] |= 0x8000;
    }
    __syncthreads();

    // --- compaction: selected ascending then unselected ascending ---
    int cnt = 0;
    for (int l = lo; l < hi; ++l) cnt += (s_pk[l] & 0x8000) ? 1 : 0x10000;
    const int pb = block_exscan_fast(cnt, s_warp, tid);
    const int S = s_warp[15] & 0xFFFF;
    int bs = pb & 0xFFFF, bu = (pb >> 16) + S;
    for (int l = lo; l < hi; ++l) {
        if (s_pk[l] & 0x8000) { if (bs < NSAMP) s_idx[bs] = l; ++bs; }
        else                  { if (bu < NSAMP) s_idx[bu] = l; ++bu; }
    }
    __syncthreads();

    // --- gather + write all 4 outputs (ints written as float values) ---
    if (tid < NSAMP) {
        const int l = s_idx[tid];
        float4 bx = (l < NN) ? bb4[l] : gb4[l - NN];
        const int p = s_pk[l];
        const int c = p & 3, mi = (p >> 2) & 0xFF;
        const bool bg = (c != 1);          // background = matched_val < 0.5
        float4 gb = make_float4(0.f, 0.f, 0.f, 0.f);
        int cl = 0, si = -1;
        if (!bg) {
            gb = gb4[mi];
            cl = gtc[(size_t)b * MM + mi];
            si = mi;
        }
        const size_t rk = (size_t)b * NSAMP + tid;
        ((float4*)out)[rk] = bx;                                   // rois
        ((float4*)(out + (size_t)BB * NSAMP * 4))[rk] = gb;        // sampled_gt_boxes
        out[(size_t)2 * BB * NSAMP * 4 + rk] = (float)cl;          // classes
        out[(size_t)2 * BB * NSAMP * 4 + (size_t)BB * NSAMP + rk] = (float)si; // indices
    }
}

extern "C" void kernel_launch(void* const* d_in, const int* in_sizes, int n_in,
                              void* d_out, int out_size, void* d_ws, size_t ws_size,
                              hipStream_t stream)
{
    const float* boxes = (const float*)d_in[0];   // [32,8000,4] f32
    const float* gt    = (const float*)d_in[1];   // [32,256,4]  f32
    const int*   gtc   = (const int*)  d_in[2];   // [32,256]    i32
    const float* rnd   = (const float*)d_in[3];   // [32,8256]   f32
    float* out = (float*)d_out;
    uint8_t*  pidx   = (uint8_t*)d_ws;                                     // 1.06 MB
    uint16_t* packed = (uint16_t*)((char*)d_ws + (size_t)BB * LL * SPLIT); // 0.53 MB

    dim3 g1((LL + 511) / 512, BB, SPLIT);         // 17,32,4 = 2176 blocks
    match_split_kernel<<<g1, 256, 0, stream>>>(boxes, gt, pidx);
    dim3 g2((LL + 255) / 256, BB);                // 33,32
    merge_kernel<<<g2, 256, 0, stream>>>(boxes, gt, pidx, packed);
    sample_kernel<<<BB, T2, 0, stream>>>(boxes, gt, gtc, rnd, packed, out);
}

// Round 19
// 66.402 us; speedup vs baseline: 1.2849x; 1.0243x over previous
//
#include <hip/hip_runtime.h>
#include <stdint.h>

#define BB 32
#define NN 8000
#define MM 256
#define LL (NN + MM)        // 8256
#define NSAMP 512
#define MAXPOS 128
#define T2 1024
#define CH ((LL + T2 - 1) / T2)   // 9
#define SPLIT 4
#define MSUB (MM / SPLIT)   // 64

// forbid fp-contract across this value (match numpy rounding); NON-volatile
__device__ __forceinline__ void opaquef(float& x) { asm("" : "+v"(x)); }

// exact reference semantics within one split (serial, IEEE div) -- rare
__device__ __noinline__ int serial_argmax(const float4 bx, const float a1,
                                          const float4* s_gt, const float* s_a2)
{
    float qb = -1.0f; int bi = 0;
    for (int m = 0; m < MSUB; ++m) {
        float4 g = s_gt[m];
        float ih = fmaxf(fminf(bx.z, g.z) - fmaxf(bx.x, g.x), 0.0f);
        float iw = fmaxf(fminf(bx.w, g.w) - fmaxf(bx.y, g.y), 0.0f);
        float inter = ih * iw; opaquef(inter);
        float uni = (a1 + s_a2[m]) - inter;        // numpy op order/rounding
        float q = (uni > 0.0f) ? (inter / uni) : 0.0f;
        if (q > qb) { qb = q; bi = m; }
    }
    return bi;
}

// ---------------- kernel 1: per-(b, box-pair, split) argmax over 64 gts ----
// BEST MEASURED MATCH (41.8us): with s = fl(a1+a2), exact identity
// i/(s-i) > j/(t-j) <=> i*t > j*s. Decision: p1 > p2*(1+2^-19) -> rounded
// quotients (the reference compares those) strictly ordered: WIN;
// p1 <= p2*(1-2^-19) -> LOSE; between (covers all exact ties and the
// boundary) -> exact serial redo with IEEE division (bit-identical to the
// reference compare). Invalid (-1) boxes/gts give inter = 0 -> never win,
// never ambiguous -> running index stays 0, matching the reference argmax
// for all -1 rows. 2 boxes/thread amortize the LDS broadcast reads.
// NEW: margin constants hoisted to SGPRs via readfirstlane (removes two
// 32-bit literals from every STEP's instruction stream).
__global__ __launch_bounds__(256) void match_split_kernel(
    const float* __restrict__ boxes, const float* __restrict__ gt,
    uint8_t* __restrict__ pidx)
{
    __shared__ float4 s_gt[MSUB];
    __shared__ float  s_a2[MSUB];
    const int b = blockIdx.y, sp = blockIdx.z, tid = threadIdx.x;
    if (tid < MSUB) {
        float4 v = ((const float4*)(gt + ((size_t)b * MM + sp * MSUB) * 4))[tid];
        s_gt[tid] = v;
        s_a2[tid] = (v.z - v.x) * (v.w - v.y);   // invalid gt (-1,...) -> 0
    }
    __syncthreads();
    const int l0 = blockIdx.x * 512 + tid * 2;
    if (l0 >= LL) return;
    const int l1 = l0 + 1;
    const bool v1 = (l1 < LL);
    const int l1c = v1 ? l1 : l0;

    // 1 +/- 2^-19, pinned to SGPRs (loop-invariant scalar operands)
    const float onep = __uint_as_float(
        (uint32_t)__builtin_amdgcn_readfirstlane(0x3F800010));
    const float onem = __uint_as_float(
        (uint32_t)__builtin_amdgcn_readfirstlane(0x3F7FFFE0));

    const float4* bb4 = (const float4*)(boxes + (size_t)b * NN * 4);
    const float4* gb4 = (const float4*)(gt + (size_t)b * MM * 4);
    float4 bx0 = (l0 < NN) ? bb4[l0] : gb4[l0 - NN];
    float4 bx1 = (l1c < NN) ? bb4[l1c] : gb4[l1c - NN];

    float a10 = (bx0.z - bx0.x) * (bx0.w - bx0.y); opaquef(a10);
    float a11 = (bx1.z - bx1.x) * (bx1.w - bx1.y); opaquef(a11);

    // 2 independent chains per box (even/odd m) for ILP; branchless updates
    float I00 = 0.f, S00 = 1.f, I01 = 0.f, S01 = 1.f;
    float I10 = 0.f, S10 = 1.f, I11 = 0.f, S11 = 1.f;
    int X00 = 0, X01 = 1, X10 = 0, X11 = 1;
    bool redo0 = false, redo1 = false;

    #define STEP(BX, A1, G, A2, BI, BS, BIX, MIDX, RD)                       \
    {                                                                        \
        float ih = fmaxf(fminf(BX.z, G.z) - fmaxf(BX.x, G.x), 0.0f);         \
        float iw = fmaxf(fminf(BX.w, G.w) - fmaxf(BX.y, G.y), 0.0f);         \
        float inter = ih * iw; opaquef(inter);                               \
        float s  = A1 + A2;                                                  \
        float p1 = inter * BS, p2 = BI * s;                                  \
        bool win = p1 > p2 * onep;                                           \
        RD |= ((p1 > p2 * onem) != win);                                     \
        if (win) { BI = inter; BS = s; BIX = MIDX; }                         \
    }
    #pragma unroll 4
    for (int m = 0; m < MSUB; m += 2) {
        float4 g0 = s_gt[m];     float a2_0 = s_a2[m];
        float4 g1 = s_gt[m + 1]; float a2_1 = s_a2[m + 1];
        STEP(bx0, a10, g0, a2_0, I00, S00, X00, m,     redo0)
        STEP(bx0, a10, g1, a2_1, I01, S01, X01, m + 1, redo0)
        STEP(bx1, a11, g0, a2_0, I10, S10, X10, m,     redo1)
        STEP(bx1, a11, g1, a2_1, I11, S11, X11, m + 1, redo1)
    }
    #undef STEP

    // merge odd chain into even: adopt only on strict win; any closeness
    // (incl. exact ties, where odd may hold the LOWER index) -> redo
    #define MERGE(I0, S0, X0, I1, S1, X1, RD)                                \
    {                                                                        \
        float p1 = I1 * S0, p2 = I0 * S1;                                    \
        bool win = p1 > p2 * onep;                                           \
        RD |= ((p1 > p2 * onem) != win);                                     \
        if (win) { X0 = X1; }                                                \
    }
    MERGE(I00, S00, X00, I01, S01, X01, redo0)
    MERGE(I10, S10, X10, I11, S11, X11, redo1)
    #undef MERGE

    int lb0 = X00, lb1 = X10;
    if (__any(redo0 || redo1)) {
        if (redo0) lb0 = serial_argmax(bx0, a10, s_gt, s_a2);
        if (redo1) lb1 = serial_argmax(bx1, a11, s_gt, s_a2);
    }
    pidx[((size_t)b * LL + l0) * SPLIT + sp] = (uint8_t)lb0;
    if (v1) pidx[((size_t)b * LL + l1) * SPLIT + sp] = (uint8_t)lb1;
}

// ---------------- kernel 1b: merge 4 split winners, exact rounded q --------
// 1056 blocks. Exact 4-way re-merge (reference op order/rounding, IEEE div);
// split ascending + strict > = global first-argmax. Classify via q >= 0.5.
__global__ __launch_bounds__(256) void merge_kernel(
    const float* __restrict__ boxes, const float* __restrict__ gt,
    const uint8_t* __restrict__ pidx, uint16_t* __restrict__ packed)
{
    const int b = blockIdx.y;
    const int l = blockIdx.x * 256 + threadIdx.x;
    if (l >= LL) return;
    float4 bx = (l < NN) ? ((const float4*)(boxes + (size_t)b * NN * 4))[l]
                         : ((const float4*)(gt + (size_t)b * MM * 4))[l - NN];
    int cls, bidx = 0;
    if (fmaxf(fmaxf(bx.x, bx.y), fmaxf(bx.z, bx.w)) < 0.0f) {
        cls = 2;   // invalid box: all sim == -1 -> invalid, argmax = 0
    } else {
        float a1 = (bx.z - bx.x) * (bx.w - bx.y); opaquef(a1);
        float qb = -1.0f;
        const uint32_t pv = *(const uint32_t*)&pidx[((size_t)b * LL + l) * SPLIT];
        #pragma unroll
        for (int sp = 0; sp < SPLIT; ++sp) {
            const int m = sp * MSUB + (int)((pv >> (8 * sp)) & 0xFFu);
            float4 g = ((const float4*)(gt + (size_t)b * MM * 4))[m];
            float a2 = (g.z - g.x) * (g.w - g.y); opaquef(a2);
            float ih = fmaxf(fminf(bx.z, g.z) - fmaxf(bx.x, g.x), 0.0f);
            float iw = fmaxf(fminf(bx.w, g.w) - fmaxf(bx.y, g.y), 0.0f);
            float inter = ih * iw; opaquef(inter);
            float uni = (a1 + a2) - inter;        // numpy op order/rounding
            float q = (uni > 0.0f) ? (inter / uni) : 0.0f;   // exact reference
            if (q > qb) { qb = q; bidx = m; }     // split order = index order
        }
        cls = (qb >= 0.5f) ? 1 : 0;   // searchsorted([0,.5,.5], right)
    }
    packed[(size_t)b * LL + l] = (uint16_t)(cls | (bidx << 2));
}

// ---------------- scans ----------------
__device__ __forceinline__ int block_exscan_fast(int v, int* wt, int tid)
{
    const int lane = tid & 63, w = tid >> 6;
    int x = v;
    #pragma unroll
    for (int off = 1; off < 64; off <<= 1) {
        int y = __shfl_up(x, off);
        if (lane >= off) x += y;
    }
    if (lane == 63) wt[w] = x;
    __syncthreads();
    if (tid < 64) {
        int t = (tid < 16) ? wt[tid] : 0;
        #pragma unroll
        for (int off = 1; off < 16; off <<= 1) {
            int y = __shfl_up(t, off);
            if (tid >= off) t += y;
        }
        if (tid < 16) wt[tid] = t;
    }
    __syncthreads();
    return ((w > 0) ? wt[w - 1] : 0) + x - v;
}

__device__ __forceinline__ int block_exscan_seg4(int v, int* wt, int tid)
{
    const int lane = tid & 63, w = tid >> 6;
    int x = v;
    #pragma unroll
    for (int off = 1; off < 64; off <<= 1) {
        int y = __shfl_up(x, off);
        if (lane >= off) x += y;
    }
    if (lane == 63) wt[w] = x;
    __syncthreads();
    if (tid < 16) {
        int t = wt[tid];
        #pragma unroll
        for (int off = 1; off < 4; off <<= 1) {
            int y = __shfl_up(t, off);
            if ((tid & 3) >= off) t += y;
        }
        wt[tid] = t;
    }
    __syncthreads();
    return (((w & 3) > 0) ? wt[w - 1] : 0) + x - v;
}

// ---------------- kernel 2: per-batch sampling + gather --------------------
// s_pk bit layout: [1:0] cls, [9:2] matched gt idx, [15] sel flag
// NEW: radix round 0's histogram (pmask = 0 -> depends on nothing) is built
// during the load pass; the select loop skips its build phase for round 0.
__global__ __launch_bounds__(T2) void sample_kernel(
    const float* __restrict__ boxes, const float* __restrict__ gt,
    const int* __restrict__ gtc, const float* __restrict__ rnd,
    const uint16_t* __restrict__ packed, float* __restrict__ out)
{
    __shared__ uint32_t s_key[LL];
    __shared__ uint16_t s_pk[LL];
    __shared__ int s_hist[512];
    __shared__ int s_warp[16];
    __shared__ int s_idx[NSAMP];
    __shared__ int s_sb[8];
    const int b = blockIdx.x, tid = threadIdx.x, lane = tid & 63;
    const float4* bb4 = (const float4*)(boxes + (size_t)b * NN * 4);
    const float4* gb4 = (const float4*)(gt + (size_t)b * MM * 4);

    if (tid == 0) s_sb[0] = 0;
    if (tid < 512) s_hist[tid] = 0;
    __syncthreads();

    int loc = 0;
    for (int l = tid; l < LL; l += T2) {
        const uint32_t k = __float_as_uint(rnd[(size_t)b * LL + l]);
        s_key[l] = k;
        uint16_t p = packed[(size_t)b * LL + l];
        s_pk[l] = p;
        int c = p & 3;
        if (c <= 1) atomicAdd(&s_hist[(c << 8) | (k >> 24)], 1);  // round 0
        loc += (c == 0) ? 1 : ((c == 1) ? 0x10000 : 0);
    }
    #pragma unroll
    for (int off = 32; off; off >>= 1) loc += __shfl_xor(loc, off);
    if (lane == 0) atomicAdd(&s_sb[0], loc);
    __syncthreads();
    const int Nn = s_sb[0] & 0xFFFF, P = s_sb[0] >> 16;

    const int posK = (P < MAXPOS) ? P : MAXPOS;
    const int negK = NSAMP - posK;
    const bool negRad = (Nn > negK);
    const bool posRad = (P > MAXPOS);

    // --- fused dual-class radix select with whole-bin early exit ---
    uint32_t prefix0 = 0, prefix1 = 0;
    int rem0 = negK, rem1 = MAXPOS;
    bool act0 = negRad, act1 = posRad;
    uint32_t thr0f = 0, thr1f = 0;
    int r0f = LL, r1f = LL;
    for (int round = 0; round < 4 && (act0 || act1); ++round) {
        const int shift = 24 - 8 * round;
        if (round > 0) {   // round 0's histogram was built in the load pass
            if (tid < 512) s_hist[tid] = 0;
            __syncthreads();
            const uint32_t pmask = 0xFFFFFFFFu << (shift + 8);
            for (int l = tid; l < LL; l += T2) {
                const uint32_t k = s_key[l];
                const int c = s_pk[l] & 3;
                bool doit = (c == 0) ? (act0 && ((k & pmask) == prefix0))
                          : (c == 1) ? (act1 && ((k & pmask) == prefix1))
                          : false;
                if (doit) atomicAdd(&s_hist[(c << 8) | ((k >> shift) & 255)], 1);
            }
            __syncthreads();
        }
        int h = 0;
        if (tid < 512) h = s_hist[(tid & 0x100) | (255 - (tid & 255))];
        const int above = block_exscan_seg4(h, s_warp, tid);
        if (tid < 512) {
            const int c = tid >> 8;
            const int rem = c ? rem1 : rem0;
            const bool act = c ? act1 : act0;
            if (act && above < rem && above + h >= rem) {
                s_sb[4 + c * 2] = 255 - (tid & 255);
                s_sb[5 + c * 2] = above;
            }
        }
        __syncthreads();
        if (act0) {
            const int bin = s_sb[4];
            rem0 -= s_sb[5];
            prefix0 |= ((uint32_t)bin) << shift;
            const int cnt = s_hist[bin];
            if (rem0 == cnt)      { act0 = false; thr0f = prefix0; r0f = LL; }
            else if (round == 3)  { act0 = false; thr0f = prefix0; r0f = rem0; }
        }
        if (act1) {
            const int bin = s_sb[6];
            rem1 -= s_sb[7];
            prefix1 |= ((uint32_t)bin) << shift;
            const int cnt = s_hist[256 + bin];
            if (rem1 == cnt)      { act1 = false; thr1f = prefix1; r1f = LL; }
            else if (round == 3)  { act1 = false; thr1f = prefix1; r1f = rem1; }
        }
        __syncthreads();
    }
    const uint32_t thr0 = negRad ? thr0f : 0u;  const int r0 = negRad ? r0f : LL;
    const uint32_t thr1 = posRad ? thr1f : 0u;  const int r1 = posRad ? r1f : LL;

    // --- fused mark pass (tie counts packed: neg low16 | pos high16) ---
    const int lo = tid * CH, hi = (lo + CH < LL) ? (lo + CH) : LL;
    int nt = 0;
    for (int l = lo; l < hi; ++l) {
        const int c = s_pk[l] & 3;
        const uint32_t k = s_key[l];
        if (c == 0) { if (k == thr0) nt += 1; }
        else if (c == 1) { if (k == thr1) nt += 0x10000; }
    }
    const int basep = block_exscan_fast(nt, s_warp, tid);
    int base0 = basep & 0xFFFF, base1 = basep >> 16;
    for (int l = lo; l < hi; ++l) {
        const int c = s_pk[l] & 3;
        if (c > 1) continue;
        const uint32_t k = s_key[l];
        const uint32_t thr = c ? thr1 : thr0;
        bool sel = (k > thr);
        if (k == thr) {
            if (c == 0) { sel = (base0 < r0); ++base0; }
            else        { sel = (base1 < r1); ++base1; }
        }
        if (sel) s_pk[l] |= 0x8000;
    }
    __syncthreads();

    // --- compaction: selected ascending then unselected ascending ---
    int cnt = 0;
    for (int l = lo; l < hi; ++l) cnt += (s_pk[l] & 0x8000) ? 1 : 0x10000;
    const int pb = block_exscan_fast(cnt, s_warp, tid);
    const int S = s_warp[15] & 0xFFFF;
    int bs = pb & 0xFFFF, bu = (pb >> 16) + S;
    for (int l = lo; l < hi; ++l) {
        if (s_pk[l] & 0x8000) { if (bs < NSAMP) s_idx[bs] = l; ++bs; }
        else                  { if (bu < NSAMP) s_idx[bu] = l; ++bu; }
    }
    __syncthreads();

    // --- gather + write all 4 outputs (ints written as float values) ---
    if (tid < NSAMP) {
        const int l = s_idx[tid];
        float4 bx = (l < NN) ? bb4[l] : gb4[l - NN];
        const int p = s_pk[l];
        const int c = p & 3, mi = (p >> 2) & 0xFF;
        const bool bg = (c != 1);          // background = matched_val < 0.5
        float4 gb = make_float4(0.f, 0.f, 0.f, 0.f);
        int cl = 0, si = -1;
        if (!bg) {
            gb = gb4[mi];
            cl = gtc[(size_t)b * MM + mi];
            si = mi;
        }
        const size_t rk = (size_t)b * NSAMP + tid;
        ((float4*)out)[rk] = bx;                                   // rois
        ((float4*)(out + (size_t)BB * NSAMP * 4))[rk] = gb;        // sampled_gt_boxes
        out[(size_t)2 * BB * NSAMP * 4 + rk] = (float)cl;          // classes
        out[(size_t)2 * BB * NSAMP * 4 + (size_t)BB * NSAMP + rk] = (float)si; // indices
    }
}

extern "C" void kernel_launch(void* const* d_in, const int* in_sizes, int n_in,
                              void* d_out, int out_size, void* d_ws, size_t ws_size,
                              hipStream_t stream)
{
    const float* boxes = (const float*)d_in[0];   // [32,8000,4] f32
    const float* gt    = (const float*)d_in[1];   // [32,256,4]  f32
    const int*   gtc   = (const int*)  d_in[2];   // [32,256]    i32
    const float* rnd   = (const float*)d_in[3];   // [32,8256]   f32
    float* out = (float*)d_out;
    uint8_t*  pidx   = (uint8_t*)d_ws;                                     // 1.06 MB
    uint16_t* packed = (uint16_t*)((char*)d_ws + (size_t)BB * LL * SPLIT); // 0.53 MB

    dim3 g1((LL + 511) / 512, BB, SPLIT);         // 17,32,4 = 2176 blocks
    match_split_kernel<<<g1, 256, 0, stream>>>(boxes, gt, pidx);
    dim3 g2((LL + 255) / 256, BB);                // 33,32
    merge_kernel<<<g2, 256, 0, stream>>>(boxes, gt, pidx, packed);
    sample_kernel<<<BB, T2, 0, stream>>>(boxes, gt, gtc, rnd, packed, out);
}